// Round 1
// baseline (428.257 us; speedup 1.0000x reference)
//
#include <hip/hip_runtime.h>

// LSTMModel: 2-layer LSTM (H=50, I=7), B=4096, T=256, + FC head to 7 outputs.
// Strategy: persistent kernel, 256 blocks x 256 threads, NB=16 batches/block.
// All matvecs via mfma_f32_16x16x32_f16 with weight B-fragments held in
// registers for the whole sequence. Gate columns padded to 4 gates x 64 units
// (256 cols = 16 N-tiles); wave w owns tiles {w, w+4, w+8, w+12} == gates
// i,f,g,o of units 16w..16w+15, so the LSTM cell update happens entirely in
// registers on the MFMA C-layout (col = lane&15, row = (lane>>4)*4 + reg).
// h1/h2 pass between timesteps through small LDS A-operand buffers.
// fp16 weights/activations, fp32 accumulation and cell state (err ~5e-4 << 3e-3 tol).

#define T_SEQ 256
#define HID 50
#define INF 7
#define NB 16
#define BLK 256

typedef _Float16 f16x8 __attribute__((ext_vector_type(8)));
typedef float f32x4 __attribute__((ext_vector_type(4)));

__device__ __forceinline__ float fast_sigmoid(float x) {
    // 1/(1+2^(-x*log2 e)); saturates cleanly (no NaN for +-inf args)
    return __builtin_amdgcn_rcpf(1.0f + __builtin_amdgcn_exp2f(x * -1.442695040888963f));
}
__device__ __forceinline__ float fast_tanh(float x) {
    // 2*sigmoid(2x)-1; saturates cleanly
    return 2.0f * __builtin_amdgcn_rcpf(1.0f + __builtin_amdgcn_exp2f(x * -2.885390081777927f)) - 1.0f;
}

__global__ __launch_bounds__(BLK, 1) void lstm2_fc_kernel(
    const float* __restrict__ x,
    const float* __restrict__ w_ih0, const float* __restrict__ w_hh0,
    const float* __restrict__ b_ih0, const float* __restrict__ b_hh0,
    const float* __restrict__ w_ih1, const float* __restrict__ w_hh1,
    const float* __restrict__ b_ih1, const float* __restrict__ b_hh1,
    const float* __restrict__ w_fc, const float* __restrict__ b_fc,
    float* __restrict__ out)
{
    // LDS: weight-staging scratch (init only) + h shuttles + final h2
    __shared__ _Float16 tmp[20000];      // 40000 B, init-time only
    __shared__ _Float16 lha[16 * 72];    // [m][k]: k 0..6 = x(t), 7..56 = h1, 57..63 = 0; stride 72 (bank-spread, 16B aligned)
    __shared__ _Float16 lhb[16 * 136];   // [m][k]: k 0..49 = h1(t), 50..99 = h2(t-1), 100..127 = 0; stride 136
    __shared__ float    lgout[16 * 52];  // final h2 (fp32) for FC

    const int tid  = threadIdx.x;
    const int w    = tid >> 6;        // wave id 0..3  -> unit group
    const int lane = tid & 63;
    const int n0   = lane & 15;       // MFMA col-within-tile / A-row m
    const int mq   = lane >> 4;       // MFMA quad: A k-block, C row-block
    const int u    = w * 16 + n0;     // hidden unit owned by this lane (u<50 real)
    const int b0   = blockIdx.x * NB;

    // ---------------- build layer-1 B-fragments (weights -> registers) -------
    // Column layout: col = gate*64 + unit (gate in {i,f,g,o} = rows g*50+u of W).
    // K layout layer1: k 0..6 = w_ih0 (vs x), k 7..56 = w_hh0 (vs h1), else 0.
    for (int i = tid; i < 1400; i += BLK)  tmp[i] = (_Float16)w_ih0[i];
    for (int i = tid; i < 10000; i += BLK) tmp[1400 + i] = (_Float16)w_hh0[i];
    __syncthreads();

    f16x8 B1[4][2];
    #pragma unroll
    for (int g = 0; g < 4; ++g) {
        const int r0 = g * 50 + u;
        #pragma unroll
        for (int c = 0; c < 2; ++c) {
            #pragma unroll
            for (int j = 0; j < 8; ++j) {
                const int k = c * 32 + mq * 8 + j;
                _Float16 v = (_Float16)0.0f;
                if (u < 50) {
                    if (k < 7)       v = tmp[r0 * 7 + k];
                    else if (k < 57) v = tmp[1400 + r0 * 50 + (k - 7)];
                }
                B1[g][c][j] = v;
            }
        }
    }
    __syncthreads();

    // ---------------- build layer-2 B-fragments ------------------------------
    // K layout layer2: k 0..49 = w_ih1 (vs h1(t)), k 50..99 = w_hh1 (vs h2(t-1)), else 0.
    for (int i = tid; i < 10000; i += BLK) tmp[i] = (_Float16)w_ih1[i];
    for (int i = tid; i < 10000; i += BLK) tmp[10000 + i] = (_Float16)w_hh1[i];
    __syncthreads();

    f16x8 B2[4][4];
    #pragma unroll
    for (int g = 0; g < 4; ++g) {
        const int r0 = g * 50 + u;
        #pragma unroll
        for (int c = 0; c < 4; ++c) {
            #pragma unroll
            for (int j = 0; j < 8; ++j) {
                const int k = c * 32 + mq * 8 + j;
                _Float16 v = (_Float16)0.0f;
                if (u < 50) {
                    if (k < 50)       v = tmp[r0 * 50 + k];
                    else if (k < 100) v = tmp[10000 + r0 * 50 + (k - 50)];
                }
                B2[g][c][j] = v;
            }
        }
    }

    // Per-lane biases (gate g of unit u)
    float bias1[4], bias2[4];
    #pragma unroll
    for (int g = 0; g < 4; ++g) {
        if (u < 50) {
            bias1[g] = b_ih0[g * 50 + u] + b_hh0[g * 50 + u];
            bias2[g] = b_ih1[g * 50 + u] + b_hh1[g * 50 + u];
        } else { bias1[g] = 0.0f; bias2[g] = 0.0f; }
    }

    // ---------------- init h buffers + stage x(0) ----------------------------
    for (int i = tid; i < 16 * 72; i += BLK)  lha[i] = (_Float16)0.0f;
    for (int i = tid; i < 16 * 136; i += BLK) lhb[i] = (_Float16)0.0f;
    __syncthreads();
    if (tid < NB * INF) {
        const int m = tid / INF, kk = tid - m * INF;
        lha[m * 72 + kk] = (_Float16)x[(b0 + m) * (T_SEQ * INF) + kk];
    }
    __syncthreads();

    float c1[4] = {0, 0, 0, 0}, c2[4] = {0, 0, 0, 0};

    // x-prefetch lane mapping (wave 3 only; its U-lanes are mostly padding)
    const int kk3 = lane & 7, m3 = lane >> 3;
    const long xstride = (long)(T_SEQ * INF);

    for (int t = 0; t < T_SEQ; ++t) {
        // prefetch x(t+1) early; written to lha late (latency hidden by 2 phases)
        float xv0 = 0.0f, xv1 = 0.0f;
        const bool stage = (w == 3) && (t + 1 < T_SEQ) && (kk3 < INF);
        if (stage) {
            xv0 = x[(b0 + m3) * xstride + (t + 1) * INF + kk3];
            xv1 = x[(b0 + m3 + 8) * xstride + (t + 1) * INF + kk3];
        }

        // ---- layer-1 gates: [x(t) | h1(t-1)] x W1^T ----
        f16x8 a1[2];
        #pragma unroll
        for (int c = 0; c < 2; ++c)
            a1[c] = *reinterpret_cast<const f16x8*>(&lha[(lane & 15) * 72 + c * 32 + mq * 8]);
        f32x4 acc[4];
        #pragma unroll
        for (int g = 0; g < 4; ++g) {
            acc[g] = (f32x4){0.0f, 0.0f, 0.0f, 0.0f};
            #pragma unroll
            for (int c = 0; c < 2; ++c)
                acc[g] = __builtin_amdgcn_mfma_f32_16x16x32_f16(a1[c], B1[g][c], acc[g], 0, 0, 0);
        }
        __syncthreads();  // b1: lha/lhb reads of this phase done -> writable

        // ---- layer-1 cell update (in registers; lane owns unit u, 4 batches) ----
        #pragma unroll
        for (int r = 0; r < 4; ++r) {
            const float gi = acc[0][r] + bias1[0];
            const float gf = acc[1][r] + bias1[1];
            const float gg = acc[2][r] + bias1[2];
            const float go = acc[3][r] + bias1[3];
            const float ct = fast_sigmoid(gf) * c1[r] + fast_sigmoid(gi) * fast_tanh(gg);
            c1[r] = ct;
            const float h = fast_sigmoid(go) * fast_tanh(ct);
            if (u < 50) {
                const int m = mq * 4 + r;
                lha[m * 72 + 7 + u]  = (_Float16)h;   // for layer-1 @ t+1
                lhb[m * 136 + u]     = (_Float16)h;   // for layer-2 @ t
            }
        }
        __syncthreads();  // b2: h1(t) visible

        // ---- layer-2 gates: [h1(t) | h2(t-1)] x W2^T ----
        f16x8 a2[4];
        #pragma unroll
        for (int c = 0; c < 4; ++c)
            a2[c] = *reinterpret_cast<const f16x8*>(&lhb[(lane & 15) * 136 + c * 32 + mq * 8]);
        #pragma unroll
        for (int g = 0; g < 4; ++g) {
            acc[g] = (f32x4){0.0f, 0.0f, 0.0f, 0.0f};
            #pragma unroll
            for (int c = 0; c < 4; ++c)
                acc[g] = __builtin_amdgcn_mfma_f32_16x16x32_f16(a2[c], B2[g][c], acc[g], 0, 0, 0);
        }
        __syncthreads();  // b3: lhb reads done -> h2 slots writable

        // ---- layer-2 cell update ----
        #pragma unroll
        for (int r = 0; r < 4; ++r) {
            const float gi = acc[0][r] + bias2[0];
            const float gf = acc[1][r] + bias2[1];
            const float gg = acc[2][r] + bias2[2];
            const float go = acc[3][r] + bias2[3];
            const float ct = fast_sigmoid(gf) * c2[r] + fast_sigmoid(gi) * fast_tanh(gg);
            c2[r] = ct;
            const float h = fast_sigmoid(go) * fast_tanh(ct);
            if (u < 50) {
                const int m = mq * 4 + r;
                lhb[m * 136 + 50 + u] = (_Float16)h;
                if (t == T_SEQ - 1) lgout[m * 52 + u] = h;  // fp32 for FC head
            }
        }
        if (stage) {  // write prefetched x(t+1) into lha cols 0..6
            lha[m3 * 72 + kk3]       = (_Float16)xv0;
            lha[(m3 + 8) * 72 + kk3] = (_Float16)xv1;
        }
        __syncthreads();  // b4
    }

    // ---------------- FC head: out = h2 @ w_fc^T + b_fc ----------------------
    if (tid < NB * INF) {
        const int m = tid / INF, o = tid - m * INF;
        float acc = b_fc[o];
        #pragma unroll
        for (int uu = 0; uu < HID; ++uu)
            acc += w_fc[o * HID + uu] * lgout[m * 52 + uu];
        out[(b0 + m) * INF + o] = acc;
    }
}

extern "C" void kernel_launch(void* const* d_in, const int* in_sizes, int n_in,
                              void* d_out, int out_size, void* d_ws, size_t ws_size,
                              hipStream_t stream) {
    const float* x     = (const float*)d_in[0];
    const float* w_ih0 = (const float*)d_in[1];
    const float* w_hh0 = (const float*)d_in[2];
    const float* b_ih0 = (const float*)d_in[3];
    const float* b_hh0 = (const float*)d_in[4];
    const float* w_ih1 = (const float*)d_in[5];
    const float* w_hh1 = (const float*)d_in[6];
    const float* b_ih1 = (const float*)d_in[7];
    const float* b_hh1 = (const float*)d_in[8];
    const float* w_fc  = (const float*)d_in[9];
    const float* b_fc  = (const float*)d_in[10];
    float* out = (float*)d_out;

    dim3 grid(4096 / NB), block(BLK);
    lstm2_fc_kernel<<<grid, block, 0, stream>>>(
        x, w_ih0, w_hh0, b_ih0, b_hh0, w_ih1, w_hh1, b_ih1, b_hh1, w_fc, b_fc, out);
}

// Round 2
// 395.082 us; speedup vs baseline: 1.0840x; 1.0840x over previous
//
#include <hip/hip_runtime.h>

// 2-layer LSTM (H=50, I=7), B=4096, T=256, + FC head. fp32 in/out.
// Round 2: single-barrier software pipeline. Layer-1(t) and layer-2(t-1) both
// consume h1(t-1), so one shared LDS A-buffer per phase, K=128 layout:
//   k 0..49  = h1(p-1)   k 50..99 = h2(p-2)   k 100..106 = x(p)   k 107..127 = 0
// B-fragments (held in registers all 257 phases):
//   layer1: k<50 -> w_hh0, k in [100,107) -> w_ih0, else 0
//   layer2: k<50 -> w_ih1, k in [50,100)  -> w_hh1, else 0
// Wave w owns gates i,f,g,o of units 16w..16w+15 (MFMA C-layout: col=lane&15,
// row=(lane>>4)*4+reg) -> cell update entirely in registers. Biases folded
// into MFMA C-init. Double-buffered shuttle, ONE __syncthreads per phase
// (vs 4 in round 1; the compiler's waitcnt-drain before s_barrier makes
// read(rb)/write(wb) with 2 buffers race-free).

#define T_SEQ 256
#define HID 50
#define INF 7
#define NB 16
#define BLK 256
#define LSTR 144  // shuttle row stride in halves (16B-aligned, spreads banks)

typedef _Float16 f16x8 __attribute__((ext_vector_type(8)));
typedef float f32x4 __attribute__((ext_vector_type(4)));

__device__ __forceinline__ float fast_sigmoid(float x) {
    return __builtin_amdgcn_rcpf(1.0f + __builtin_amdgcn_exp2f(x * -1.442695040888963f));
}
__device__ __forceinline__ float fast_tanh(float x) {
    return 2.0f * __builtin_amdgcn_rcpf(1.0f + __builtin_amdgcn_exp2f(x * -2.885390081777927f)) - 1.0f;
}

__global__ __launch_bounds__(BLK, 1) void lstm2_fc_kernel(
    const float* __restrict__ x,
    const float* __restrict__ w_ih0, const float* __restrict__ w_hh0,
    const float* __restrict__ b_ih0, const float* __restrict__ b_hh0,
    const float* __restrict__ w_ih1, const float* __restrict__ w_hh1,
    const float* __restrict__ b_ih1, const float* __restrict__ b_hh1,
    const float* __restrict__ w_fc, const float* __restrict__ b_fc,
    float* __restrict__ out)
{
    __shared__ _Float16 lhs[2][16 * LSTR];  // double-buffered [h1|h2|x] shuttle
    __shared__ float    lgout[16 * 52];     // final h2 (fp32) for FC head

    const int tid  = threadIdx.x;
    const int w    = tid >> 6;
    const int lane = tid & 63;
    const int n0   = lane & 15;   // MFMA col-within-tile / A row m
    const int mq   = lane >> 4;   // quad: A k-block, C row-block
    const int u    = w * 16 + n0; // hidden unit owned by this lane
    const int b0   = blockIdx.x * NB;

    // ---- weight B-fragments: global -> registers (one-time; weights are
    //      120 KB total -> L2/L3 resident after first few blocks) ----
    f16x8 B1[4][4], B2[4][4];
    #pragma unroll
    for (int g = 0; g < 4; ++g) {
        const int r0 = g * HID + u;
        #pragma unroll
        for (int c = 0; c < 4; ++c) {
            #pragma unroll
            for (int j = 0; j < 8; ++j) {
                const int k = c * 32 + mq * 8 + j;
                float v1 = 0.0f, v2 = 0.0f;
                if (u < HID) {
                    if (k < 50)        { v1 = w_hh0[r0 * 50 + k];        v2 = w_ih1[r0 * 50 + k]; }
                    else if (k < 100)  { v2 = w_hh1[r0 * 50 + (k - 50)]; }
                    else if (k < 107)  { v1 = w_ih0[r0 * 7 + (k - 100)]; }
                }
                B1[g][c][j] = (_Float16)v1;
                B2[g][c][j] = (_Float16)v2;
            }
        }
    }

    float bias1[4], bias2[4];
    #pragma unroll
    for (int g = 0; g < 4; ++g) {
        if (u < HID) {
            bias1[g] = b_ih0[g * HID + u] + b_hh0[g * HID + u];
            bias2[g] = b_ih1[g * HID + u] + b_hh1[g * HID + u];
        } else { bias1[g] = 0.0f; bias2[g] = 0.0f; }
    }

    // ---- init shuttle (zeros = h(-1)=0, c(-1)=0) + stage x(0) ----
    for (int i = tid; i < 2 * 16 * LSTR; i += BLK) (&lhs[0][0])[i] = (_Float16)0.0f;
    __syncthreads();
    if (tid < NB * INF) {
        const int m = tid / INF, kk = tid - m * INF;
        lhs[0][m * LSTR + 100 + kk] = (_Float16)x[(b0 + m) * (T_SEQ * INF) + kk];
    }
    __syncthreads();

    float c1[4] = {0, 0, 0, 0}, c2[4] = {0, 0, 0, 0};

    const int kk3 = lane & 7, m3 = lane >> 3;  // x-prefetch mapping (wave 3)
    const long xstride = (long)(T_SEQ * INF);

    // Phase p: layer1 computes t=p (p<256); layer2 computes t=p-1 (p>=1).
    for (int p = 0; p <= T_SEQ; ++p) {
        const int rb = p & 1, wbuf = rb ^ 1;

        // prefetch x(p+1) early (consumed late-phase; HBM latency hidden)
        float xv0 = 0.0f, xv1 = 0.0f;
        const bool stage = (w == 3) && (p + 1 < T_SEQ) && (kk3 < INF);
        if (stage) {
            xv0 = x[(b0 + m3) * xstride + (p + 1) * INF + kk3];
            xv1 = x[(b0 + m3 + 8) * xstride + (p + 1) * INF + kk3];
        }

        // shared A-fragments: [h1(p-1) | h2(p-2) | x(p) | 0]
        f16x8 a[4];
        #pragma unroll
        for (int c = 0; c < 4; ++c)
            a[c] = *reinterpret_cast<const f16x8*>(&lhs[rb][n0 * LSTR + c * 32 + mq * 8]);

        f32x4 acc1[4], acc2[4];
        if (p < T_SEQ) {
            #pragma unroll
            for (int g = 0; g < 4; ++g) {
                acc1[g] = (f32x4){bias1[g], bias1[g], bias1[g], bias1[g]};
                #pragma unroll
                for (int c = 0; c < 4; ++c)
                    acc1[g] = __builtin_amdgcn_mfma_f32_16x16x32_f16(a[c], B1[g][c], acc1[g], 0, 0, 0);
            }
        }
        if (p >= 1) {
            #pragma unroll
            for (int g = 0; g < 4; ++g) {
                acc2[g] = (f32x4){bias2[g], bias2[g], bias2[g], bias2[g]};
                #pragma unroll
                for (int c = 0; c < 4; ++c)
                    acc2[g] = __builtin_amdgcn_mfma_f32_16x16x32_f16(a[c], B2[g][c], acc2[g], 0, 0, 0);
            }
        }

        // layer-1 cell update -> h1(p) into wbuf cols 0..49
        if (p < T_SEQ) {
            #pragma unroll
            for (int r = 0; r < 4; ++r) {
                const float gi = acc1[0][r], gf = acc1[1][r], gg = acc1[2][r], go = acc1[3][r];
                const float ct = fast_sigmoid(gf) * c1[r] + fast_sigmoid(gi) * fast_tanh(gg);
                c1[r] = ct;
                const float h = fast_sigmoid(go) * fast_tanh(ct);
                if (u < HID) lhs[wbuf][(mq * 4 + r) * LSTR + u] = (_Float16)h;
            }
        }
        // layer-2 cell update -> h2(p-1) into wbuf cols 50..99
        if (p >= 1) {
            #pragma unroll
            for (int r = 0; r < 4; ++r) {
                const float gi = acc2[0][r], gf = acc2[1][r], gg = acc2[2][r], go = acc2[3][r];
                const float ct = fast_sigmoid(gf) * c2[r] + fast_sigmoid(gi) * fast_tanh(gg);
                c2[r] = ct;
                const float h = fast_sigmoid(go) * fast_tanh(ct);
                if (u < HID) {
                    lhs[wbuf][(mq * 4 + r) * LSTR + 50 + u] = (_Float16)h;
                    if (p == T_SEQ) lgout[(mq * 4 + r) * 52 + u] = h;
                }
            }
        }
        if (stage) {
            lhs[wbuf][m3 * LSTR + 100 + kk3]       = (_Float16)xv0;
            lhs[wbuf][(m3 + 8) * LSTR + 100 + kk3] = (_Float16)xv1;
        }
        __syncthreads();  // the ONLY barrier per phase
    }

    // ---- FC head: out = h2(T-1) @ w_fc^T + b_fc ----
    if (tid < NB * INF) {
        const int m = tid / INF, o = tid - m * INF;
        float acc = b_fc[o];
        #pragma unroll
        for (int uu = 0; uu < HID; ++uu)
            acc += w_fc[o * HID + uu] * lgout[m * 52 + uu];
        out[(b0 + m) * INF + o] = acc;
    }
}

extern "C" void kernel_launch(void* const* d_in, const int* in_sizes, int n_in,
                              void* d_out, int out_size, void* d_ws, size_t ws_size,
                              hipStream_t stream) {
    const float* x     = (const float*)d_in[0];
    const float* w_ih0 = (const float*)d_in[1];
    const float* w_hh0 = (const float*)d_in[2];
    const float* b_ih0 = (const float*)d_in[3];
    const float* b_hh0 = (const float*)d_in[4];
    const float* w_ih1 = (const float*)d_in[5];
    const float* w_hh1 = (const float*)d_in[6];
    const float* b_ih1 = (const float*)d_in[7];
    const float* b_hh1 = (const float*)d_in[8];
    const float* w_fc  = (const float*)d_in[9];
    const float* b_fc  = (const float*)d_in[10];
    float* out = (float*)d_out;

    dim3 grid(4096 / NB), block(BLK);
    lstm2_fc_kernel<<<grid, block, 0, stream>>>(
        x, w_ih0, w_hh0, b_ih0, b_hh0, w_ih1, w_hh1, b_ih1, b_hh1, w_fc, b_fc, out);
}

// Round 3
// 321.635 us; speedup vs baseline: 1.3315x; 1.2284x over previous
//
#include <hip/hip_runtime.h>

// 2-layer LSTM (H=50, I=7), B=4096, T=256, + FC head. fp32 in/out.
// Round 3: layer-split wave specialization. Block = 512 (8 waves), grid = 256.
// Waves 0-3 compute layer-1 at t=p; waves 4-7 compute layer-2 at t=p-1
// (software-pipeline skew from round 2 makes both consume only lhs[rb]).
// Each wave holds ONE layer's B-fragments (64 VGPRs), does 16 MFMAs and one
// layer's cell update -> per-wave work halves, 2 waves/SIMD interleave to
// hide ds_read/MFMA/trans latency that round 2 (1 wave/SIMD) left exposed.
// Shared LDS A-buffer per phase, K=128 layout:
//   k 0..49 = h1(p-1) | k 50..99 = h2(p-2) | k 100..106 = x(p) | else 0
// Wave wl owns gates i,f,g,o of units 16*wl..16*wl+15 (MFMA C-layout:
// col=lane&15, row=(lane>>4)*4+reg) -> cell update entirely in registers.
// Biases folded into MFMA C-init. One __syncthreads per phase.

#define T_SEQ 256
#define HID 50
#define INF 7
#define NB 16
#define BLK 512
#define LSTR 144  // shuttle row stride in halves (16B-aligned, spreads banks)

typedef _Float16 f16x8 __attribute__((ext_vector_type(8)));
typedef float f32x4 __attribute__((ext_vector_type(4)));

__device__ __forceinline__ float fast_sigmoid(float x) {
    return __builtin_amdgcn_rcpf(1.0f + __builtin_amdgcn_exp2f(x * -1.442695040888963f));
}
__device__ __forceinline__ float fast_tanh(float x) {
    return 2.0f * __builtin_amdgcn_rcpf(1.0f + __builtin_amdgcn_exp2f(x * -2.885390081777927f)) - 1.0f;
}

__global__ __launch_bounds__(BLK, 2) void lstm2_fc_kernel(
    const float* __restrict__ x,
    const float* __restrict__ w_ih0, const float* __restrict__ w_hh0,
    const float* __restrict__ b_ih0, const float* __restrict__ b_hh0,
    const float* __restrict__ w_ih1, const float* __restrict__ w_hh1,
    const float* __restrict__ b_ih1, const float* __restrict__ b_hh1,
    const float* __restrict__ w_fc, const float* __restrict__ b_fc,
    float* __restrict__ out)
{
    __shared__ _Float16 lhs[2][16 * LSTR];  // double-buffered [h1|h2|x] shuttle
    __shared__ float    lgout[16 * 52];     // final h2 (fp32) for FC head

    const int tid   = threadIdx.x;
    const int w     = tid >> 6;      // wave 0..7
    const int layer = w >> 2;        // 0: layer-1 group, 1: layer-2 group
    const int wl    = w & 3;         // unit-group within layer
    const int lane  = tid & 63;
    const int n0    = lane & 15;     // MFMA col-within-tile / A row m
    const int mq    = lane >> 4;     // quad: A k-block, C row-block
    const int u     = wl * 16 + n0;  // hidden unit owned by this lane
    const int b0    = blockIdx.x * NB;

    // ---- this wave's layer's B-fragments: global -> registers (one-time) ----
    // layer 0: k<50 -> w_hh0 (vs h1), k in [100,107) -> w_ih0 (vs x), else 0
    // layer 1: k<50 -> w_ih1 (vs h1), k in [50,100)  -> w_hh1 (vs h2), else 0
    f16x8 Bf[4][4];
    #pragma unroll
    for (int g = 0; g < 4; ++g) {
        const int r0 = g * HID + u;
        #pragma unroll
        for (int c = 0; c < 4; ++c) {
            #pragma unroll
            for (int j = 0; j < 8; ++j) {
                const int k = c * 32 + mq * 8 + j;
                float v = 0.0f;
                if (u < HID) {
                    if (layer == 0) {
                        if (k < 50)                   v = w_hh0[r0 * 50 + k];
                        else if (k >= 100 && k < 107) v = w_ih0[r0 * 7 + (k - 100)];
                    } else {
                        if (k < 50)                   v = w_ih1[r0 * 50 + k];
                        else if (k < 100)             v = w_hh1[r0 * 50 + (k - 50)];
                    }
                }
                Bf[g][c][j] = (_Float16)v;
            }
        }
    }

    float bias[4];
    #pragma unroll
    for (int g = 0; g < 4; ++g) {
        if (u < HID)
            bias[g] = (layer == 0) ? (b_ih0[g * HID + u] + b_hh0[g * HID + u])
                                   : (b_ih1[g * HID + u] + b_hh1[g * HID + u]);
        else bias[g] = 0.0f;
    }

    // ---- init shuttle (zeros = h(-1)=0) + stage x(0) ----
    for (int i = tid; i < 2 * 16 * LSTR; i += BLK) (&lhs[0][0])[i] = (_Float16)0.0f;
    __syncthreads();
    if (tid < NB * INF) {
        const int m = tid / INF, kk = tid - m * INF;
        lhs[0][m * LSTR + 100 + kk] = (_Float16)x[(b0 + m) * (T_SEQ * INF) + kk];
    }
    __syncthreads();

    float cst[4] = {0, 0, 0, 0};  // this lane's cell state (its layer)

    const int kk3 = lane & 7, m3 = lane >> 3;  // x-prefetch mapping (wave 7)
    const long xstride = (long)(T_SEQ * INF);

    // Phase p: layer-1 waves compute t=p (p<256); layer-2 waves t=p-1 (p>=1).
    for (int p = 0; p <= T_SEQ; ++p) {
        const int rb = p & 1, wbuf = rb ^ 1;

        // prefetch x(p+1) early (consumed late-phase; HBM latency hidden)
        float xv0 = 0.0f, xv1 = 0.0f;
        const bool stage = (w == 7) && (p + 1 < T_SEQ) && (kk3 < INF);
        if (stage) {
            xv0 = x[(b0 + m3) * xstride + (p + 1) * INF + kk3];
            xv1 = x[(b0 + m3 + 8) * xstride + (p + 1) * INF + kk3];
        }

        // shared A-fragments: [h1(p-1) | h2(p-2) | x(p) | 0]
        f16x8 a[4];
        #pragma unroll
        for (int c = 0; c < 4; ++c)
            a[c] = *reinterpret_cast<const f16x8*>(&lhs[rb][n0 * LSTR + c * 32 + mq * 8]);

        const bool active = (layer == 0) ? (p < T_SEQ) : (p >= 1);
        if (active) {
            f32x4 acc[4];
            #pragma unroll
            for (int g = 0; g < 4; ++g) {
                acc[g] = (f32x4){bias[g], bias[g], bias[g], bias[g]};
                #pragma unroll
                for (int c = 0; c < 4; ++c)
                    acc[g] = __builtin_amdgcn_mfma_f32_16x16x32_f16(a[c], Bf[g][c], acc[g], 0, 0, 0);
            }
            // cell update (lane owns unit u of its layer, 4 batches)
            #pragma unroll
            for (int r = 0; r < 4; ++r) {
                const float gi = acc[0][r], gf = acc[1][r], gg = acc[2][r], go = acc[3][r];
                const float ct = fast_sigmoid(gf) * cst[r] + fast_sigmoid(gi) * fast_tanh(gg);
                cst[r] = ct;
                const float h = fast_sigmoid(go) * fast_tanh(ct);
                if (u < HID) {
                    const int m = mq * 4 + r;
                    lhs[wbuf][m * LSTR + layer * 50 + u] = (_Float16)h;
                    if (layer == 1 && p == T_SEQ) lgout[m * 52 + u] = h;
                }
            }
        }
        if (stage) {
            lhs[wbuf][m3 * LSTR + 100 + kk3]       = (_Float16)xv0;
            lhs[wbuf][(m3 + 8) * LSTR + 100 + kk3] = (_Float16)xv1;
        }
        __syncthreads();  // the ONLY barrier per phase
    }

    // ---- FC head: out = h2(T-1) @ w_fc^T + b_fc ----
    if (tid < NB * INF) {
        const int m = tid / INF, o = tid - m * INF;
        float acc = b_fc[o];
        #pragma unroll
        for (int uu = 0; uu < HID; ++uu)
            acc += w_fc[o * HID + uu] * lgout[m * 52 + uu];
        out[(b0 + m) * INF + o] = acc;
    }
}

extern "C" void kernel_launch(void* const* d_in, const int* in_sizes, int n_in,
                              void* d_out, int out_size, void* d_ws, size_t ws_size,
                              hipStream_t stream) {
    const float* x     = (const float*)d_in[0];
    const float* w_ih0 = (const float*)d_in[1];
    const float* w_hh0 = (const float*)d_in[2];
    const float* b_ih0 = (const float*)d_in[3];
    const float* b_hh0 = (const float*)d_in[4];
    const float* w_ih1 = (const float*)d_in[5];
    const float* w_hh1 = (const float*)d_in[6];
    const float* b_ih1 = (const float*)d_in[7];
    const float* b_hh1 = (const float*)d_in[8];
    const float* w_fc  = (const float*)d_in[9];
    const float* b_fc  = (const float*)d_in[10];
    float* out = (float*)d_out;

    dim3 grid(4096 / NB), block(BLK);
    lstm2_fc_kernel<<<grid, block, 0, stream>>>(
        x, w_ih0, w_hh0, b_ih0, b_hh0, w_ih1, w_hh1, b_ih1, b_hh1, w_fc, b_fc, out);
}